// Round 9
// baseline (237.926 us; speedup 1.0000x reference)
//
#include <hip/hip_runtime.h>
#include <hip/hip_bf16.h>
#include <math.h>

// ---------------------------------------------------------------------------
// VAE ELBO (chromatin VAE). Sizes fixed by the reference.
//
//  * NB_ENC == NB_DEC == 16, identical binning => ONE nibble histogram serves
//    both the encoder input (log1p counts) and the mixture likelihood.
//  * r3-r5: global per-record atomics too slow => two-phase LDS counting sort.
//  * r7: same-address atomics serialize ~16ns => spread slots / staggered.
//  * r12: hipLaunchCooperativeKernel DOES NOT RUN under this harness.
//  * r14: __threadfence = L2 wb/inv on 8 non-coherent XCD L2s => +138us. BAN.
//  * r15: fence-free cross-block dataflow: device-scope atomics at the
//    coherent point; returning-atomic data-dep orders signals. No fences.
//  * r16: swapped-operand MFMA => lane-local softmax; Poisson fused in.
//  * r17/r18: partition granularity + LDS/occupancy lessons (reverted).
//  * r19: mid split by CELLS (2 blocks/bucket, 32KB, grid 768). WIN.
//  * r20: part rank-from-count (no scatter atomics); mixpois (1000,2).
//  * r21: merged relaid [cg*2+half][bin][4w] (contiguous 16KB/block, no
//    sector RMW); log1p via table.
//  * r22 (this round): gap accounting says ~20-25us per dispatch boundary
//    (~100us of 219 total) => cut the chain 5->4 nodes. latent FUSED into
//    mid as role blocks [768,968): all 968 blocks co-resident by
//    construction (32KB LDS => 5/CU = 1280 slots; __launch_bounds__(256,4)
//    guarantees >=1024) => bounded spin is deadlock-free with NO dispatch-
//    order assumption. hT via returning atomicAdd + syncthreads(vmcnt drain)
//    + cutdone signal; latent polls with agent-scope atomic LOADS + s_sleep.
//    log1p LUT -> wave shfl table (ds_bpermute, zero LDS) => LDS exactly
//    32768 again.
// ---------------------------------------------------------------------------

#define G_      1000
#define C_      1024
#define L_      50
#define K_      16
#define NHID_   16
#define CUT_SCALE   12.5f          // N_TOTAL_CUTS / N_CUTS
#define CELL_SCALE  9.765625f      // N_TOTAL_CELLS / N_CELLS

#define CHUNK_    6144
#define RCAP_CUT  18432            // bucket capacity, cuts  (mean 16000)
#define RCAP_FRAG 9216             // bucket capacity, frags (mean 8000)

// ws layout (bytes); [0, ZERO_BYTES) memset per call (gcnt + done + dacc + hT).
#define GCNTC_OFF  0ull
#define GCNTF_OFF  1024ull
#define DONE_OFF   2048ull         // u32: 64 slots @16, lvl2 @[1024], cutdone @[1040]
#define DACC_OFF   6400ull         // f64[64] global ELBO accumulator slots
#define HT_OFF     6912ull         // f32 [16][1024] (atomic-accumulated by mid)
#define ZERO_BYTES 72448ull
#define LATBF_OFF  72448ull        // bf16 [1024][64]
#define LWT_OFF    203520ull       // bf16 [1000][16][64]
#define ENTC_OFF   2251520ull      // u16 [256][18432]
#define ENTF_OFF   11688704ull     // u16 [256][9216]
#define MERGED_OFF 16407296ull     // u32 [32 cg*2+half][16000 bin][4 w]
#define FRAGU8_OFF 24599296ull     // u8  [1000][1024]
#define LATT_OFF   25623296ull     // f32 [50][1024]
#define WS_NEED    25828096ull

typedef __attribute__((ext_vector_type(8))) short short8;
typedef __attribute__((ext_vector_type(4))) float f32x4;

__device__ __constant__ float LGT[32] = {   // log(n!)
    0.0f, 0.0f, 0.6931471805599453f, 1.791759469228055f, 3.1780538303479458f,
    4.787491742782046f, 6.579251212010101f, 8.525161361065415f,
    10.60460290274525f, 12.801827480081469f, 15.104412573075516f,
    17.502307845873887f, 19.987214495661885f, 22.552163853123425f,
    25.19122118273868f, 27.89927138384089f, 30.671860106080672f,
    33.50507345013689f, 36.39544520803305f, 39.339884187199495f,
    42.335616460753485f, 45.38013889847691f, 48.47118135183523f,
    51.60667556776438f, 54.78472939811232f, 58.00360522298052f,
    61.261701761002f, 64.55753862700633f, 67.88974313718154f,
    71.25703896716801f, 74.65823634883016f, 78.0922235533153f };

// f64 atomic add at the device coherent point (returns old value; the return
// is used to fabricate ordering dependencies — NO fences anywhere).
__device__ __forceinline__ double atomAddF64(double* p, double v) {
    return __hip_atomic_fetch_add(p, v, __ATOMIC_RELAXED,
                                  __HIP_MEMORY_SCOPE_AGENT);
}

__device__ __forceinline__ float block_sum_256(float v) {
    __shared__ float sm[256];
    int t = threadIdx.x;
    __syncthreads();
    sm[t] = v;
    __syncthreads();
#pragma unroll
    for (int s = 128; s > 0; s >>= 1) {
        if (t < s) sm[t] += sm[t + s];
        __syncthreads();
    }
    return sm[0];
}

// --- 1. part: [0,nblk_part) radix partition (rank-from-count, no scatter
//        atomics) | [nblk_part, +256) lwprep | [+256, +512) wkl -------------
__global__ __launch_bounds__(256)
void part_kernel(const int* __restrict__ cut_ix,
                 const float* __restrict__ coord,
                 const int* __restrict__ frag_ix,
                 unsigned int* __restrict__ gcnt_c,
                 unsigned int* __restrict__ gcnt_f,
                 unsigned short* __restrict__ entc,
                 unsigned short* __restrict__ entf,
                 const float* __restrict__ lw,      // [1000][50][16]
                 const float* __restrict__ rw,      // [1000][50]
                 __hip_bfloat16* __restrict__ lwT,  // [1000][16][64]
                 double* __restrict__ dacc,         // [64]
                 int n_cuts, int n_frags, int ncc, int nblk_part) {
    int t = threadIdx.x;
    int bid = blockIdx.x;
    if (bid >= nblk_part) {
        int r = bid - nblk_part;
        if (r < 256) {
            // ---- lwprep: bf16 transpose [g][n][64], k-pads zeroed ----
            for (int g = r; g < G_; g += 256) {
                for (int i = t; i < L_ * K_; i += 256) {
                    float v = lw[(size_t)g * (L_ * K_) + i];
                    lwT[(size_t)g * 1024 + (i & 15) * 64 + (i >> 4)] =
                        __float2bfloat16(v);
                }
                for (int i = t; i < 16 * 14; i += 256) {
                    int n = i / 14, l = 50 + (i % 14);
                    lwT[(size_t)g * 1024 + n * 64 + l] = __float2bfloat16(0.f);
                }
            }
        } else {
            // ---- weight KL ----
            const int NTOT = G_ * L_ * K_ + G_ * L_;   // 850000
            int wb = r - 256;
            float s = 0.f;
            for (int i = wb * 256 + t; i < NTOT; i += 256 * 256) {
                float w = (i < G_ * L_ * K_) ? lw[i] : rw[i - G_ * L_ * K_];
                s += fmaf(-50.f * w, w, 1.3836465597893733f);
            }
            s = block_sum_256(s);
            if (t == 0) atomAddF64(&dacc[wb & 63], (double)(-s));
        }
        return;
    }
    // ---- radix partition, one 6144-record chunk per block ----
    __shared__ unsigned int cnt[256], excl[256], gbas[256];
    __shared__ unsigned short stage[CHUNK_];
    __shared__ unsigned char bkof[CHUNK_];
    bool isCut = (bid < ncc);
    int blk = isCut ? bid : bid - ncc;
    const int* idx = isCut ? cut_ix : frag_ix;
    int n = isCut ? n_cuts : n_frags;
    int rcap = isCut ? RCAP_CUT : RCAP_FRAG;
    unsigned int* gcount = isCut ? gcnt_c : gcnt_f;
    unsigned short* ent = isCut ? entc : entf;
    int i0 = blk * CHUNK_;
    cnt[t] = 0;
    // stage 24 records in registers: 6 int4 (+6 float4 for cuts), all in flight
    int4 I[6]; float4 X[6];
    unsigned int vm;
    bool full = (i0 + CHUNK_ <= n);
    if (full) {
        const int4* ip = (const int4*)(idx + i0);
#pragma unroll
        for (int k = 0; k < 6; ++k) I[k] = ip[k * 256 + t];
        if (isCut) {
            const float4* xp = (const float4*)(coord + i0);
#pragma unroll
            for (int k = 0; k < 6; ++k) X[k] = xp[k * 256 + t];
        }
        vm = 0xFFFFFFu;
    } else {
        vm = 0;
#pragma unroll
        for (int k = 0; k < 6; ++k) {
            int r0 = i0 + (k * 256 + t) * 4;
            int* Ii = (int*)&I[k]; float* Xi = (float*)&X[k];
#pragma unroll
            for (int u = 0; u < 4; ++u) {
                bool v = (r0 + u) < n;
                if (v) vm |= 1u << (k * 4 + u);
                Ii[u] = v ? idx[r0 + u] : 0;
                Xi[u] = (v && isCut) ? coord[r0 + u] : 0.f;
            }
        }
    }
    __syncthreads();
    // count phase: compute (e,bk) ONCE, rank = returning atomic; cache all
    // three in the now-dead I/X registers (r20).
#pragma unroll
    for (int k = 0; k < 6; ++k) {
        int* Ii = (int*)&I[k];
        unsigned int* Xi = (unsigned int*)&X[k];
#pragma unroll
        for (int u = 0; u < 4; ++u) {
            if (vm & (1u << (k * 4 + u))) {
                int ix = Ii[u];
                int c = ix / G_;
                int g = ix - c * G_;
                unsigned int bk; unsigned int e;
                if (isCut) {
                    float xf = ((const float*)Xi)[u];
                    int b = (int)(xf * 16.f); b = b > 15 ? 15 : b;
                    int bin = g * K_ + b;
                    bk = ((unsigned)(c >> 6) << 4) | ((unsigned)bin >> 10);
                    e = ((unsigned)(c & 63) << 10) | ((unsigned)bin & 1023u);
                } else {
                    bk = ((unsigned)(c >> 6) << 4) | ((unsigned)g >> 6);
                    e = ((unsigned)(c & 63) << 6) | ((unsigned)g & 63u);
                }
                unsigned int rank = atomicAdd(&cnt[bk], 1u);  // LDS, returning
                Ii[u] = (int)(e | (bk << 16));
                Xi[u] = rank;
            }
        }
    }
    __syncthreads();
    // exclusive prefix over 256 bucket counts, single wave, shfl scan
    if (t < 64) {
        unsigned int c0 = cnt[t * 4 + 0], c1 = cnt[t * 4 + 1];
        unsigned int c2 = cnt[t * 4 + 2], c3 = cnt[t * 4 + 3];
        unsigned int tot = c0 + c1 + c2 + c3;
        unsigned int run = tot;
#pragma unroll
        for (int o = 1; o < 64; o <<= 1) {
            unsigned int v = __shfl_up(run, o, 64);
            if (t >= o) run += v;
        }
        unsigned int base = run - tot;          // exclusive over 4-groups
        excl[t * 4 + 0] = base;
        excl[t * 4 + 1] = base + c0;
        excl[t * 4 + 2] = base + c0 + c1;
        excl[t * 4 + 3] = base + c0 + c1 + c2;
    }
    __syncthreads();
    gbas[t] = cnt[t] ? atomicAdd(&gcount[t], cnt[t]) : 0u;  // global reserve
    // scatter from registers: p = excl[bk] + rank — NO atomics (r20)
#pragma unroll
    for (int k = 0; k < 6; ++k) {
        const unsigned int* Ii = (const unsigned int*)&I[k];
        const unsigned int* Xi = (const unsigned int*)&X[k];
#pragma unroll
        for (int u = 0; u < 4; ++u) {
            if (vm & (1u << (k * 4 + u))) {
                unsigned int w = Ii[u];
                unsigned int bk = w >> 16;
                unsigned int p = excl[bk] + Xi[u];
                stage[p] = (unsigned short)(w & 0xffffu);
                bkof[p] = (unsigned char)bk;
            }
        }
    }
    __syncthreads();
    int total = n - i0; if (total > CHUNK_) total = CHUNK_;
    for (int p = t; p < total; p += 256) {
        unsigned int bk = bkof[p];
        unsigned int dst = gbas[bk] + (p - excl[bk]);
        if (dst < (unsigned)rcap)
            ent[(size_t)bk * rcap + dst] = stage[p];
    }
}

// --- 2. mid kernel: [0,512) cut hist+enc | [512,768) frag | [768,968)
//        latent (spin on cutdone) --------------------------------------------
// All 968 blocks co-resident (32KB LDS => 5/CU = 1280 slots; launch_bounds
// guarantees >=4/CU = 1024) => spin is deadlock-free, no order assumption.
__global__ __launch_bounds__(256, 4)
void mid_kernel(const unsigned int* __restrict__ gcnt_c,
                const unsigned short* __restrict__ entc,
                const unsigned int* __restrict__ gcnt_f,
                const unsigned short* __restrict__ entf,
                const float* __restrict__ W1,        // [16000][16]
                unsigned int* __restrict__ merged,   // [32][16000][4]
                unsigned int* __restrict__ fragw,    // u8[1000][1024] as u32
                float* __restrict__ hT,              // [16][1024], pre-zeroed
                const float* __restrict__ gamma,
                const float* __restrict__ beta,
                const float* __restrict__ W_loc,     // [16][50]
                const float* __restrict__ b_loc,
                const float* __restrict__ W_scale,   // [16][50]
                const float* __restrict__ b_scale,
                const float* __restrict__ eps,       // [1024][50]
                float* __restrict__ latT,            // [50][1024]
                __hip_bfloat16* __restrict__ latbf,  // [1024][64]
                double* __restrict__ dacc,           // [64]
                unsigned int* __restrict__ done) {   // cutdone @ [1040]
    __shared__ unsigned int h[4096];   // 16 KB
    __shared__ float w1s[4096];        // 16 KB (role-local reuse)
    int t = threadIdx.x;
    int bid = blockIdx.x;
    if (bid < 512) {
        // ---- half-cell bucket: 1024 bins x 32 cells ----
        int bk = bid >> 1, half = bid & 1;
        int cg = bk >> 4, bc = bk & 15;
        for (int i = t; i < 4096; i += 256) h[i] = 0;
        // wave shfl log-table: lanes 0-15 hold log(1..16) (r22, zero LDS)
        float logtab = __logf((float)((t & 15) + 1));
        __syncthreads();
        unsigned int count = gcnt_c[bk];
        if (count > RCAP_CUT) count = RCAP_CUT;
        const unsigned int* e32 = (const unsigned int*)(entc + (size_t)bk * RCAP_CUT);
        unsigned int hsel = (unsigned)half << 5;
        unsigned int npair = count >> 1;
        for (unsigned int base = 0; base < npair; base += 1024) {
            unsigned int w[4]; bool val[4];
#pragma unroll
            for (int u = 0; u < 4; ++u) {
                unsigned int p = base + u * 256 + t;
                val[u] = (p < npair);
                w[u] = val[u] ? e32[p] : 0u;
            }
#pragma unroll
            for (int u = 0; u < 4; ++u) {
                if (val[u]) {
                    unsigned int v0 = w[u] & 0xffffu, v1 = w[u] >> 16;
                    unsigned int c0 = v0 >> 10, c1 = v1 >> 10;
                    if ((c0 & 32u) == hsel) {
                        unsigned int cc = c0 & 31u;
                        atomicAdd(&h[(v0 & 1023u) * 4 + (cc >> 3)],
                                  1u << ((cc & 7) * 4));
                    }
                    if ((c1 & 32u) == hsel) {
                        unsigned int cc = c1 & 31u;
                        atomicAdd(&h[(v1 & 1023u) * 4 + (cc >> 3)],
                                  1u << ((cc & 7) * 4));
                    }
                }
            }
        }
        if (t == 0 && (count & 1u)) {
            unsigned int v = ((const unsigned short*)e32)[count - 1];
            unsigned int c0 = v >> 10;
            if ((c0 & 32u) == hsel) {
                unsigned int cc = c0 & 31u;
                atomicAdd(&h[(v & 1023u) * 4 + (cc >> 3)], 1u << ((cc & 7) * 4));
            }
        }
        __syncthreads();
        // merged: ONE contiguous 16KB run per block (r21). bc==15 has only
        // 640 live bin rows (g*16+b <= 15999).
        {
            unsigned int mbase = ((unsigned)(cg * 2 + half)) * 64000u
                               + (unsigned)bc * 4096u;
            int lim = (bc == 15) ? 2560 : 4096;
            for (int i = t; i < lim; i += 256)
                merged[mbase + i] = h[i];
        }
        // ---- encoder: 1024 rows x 32 cells, 4 chunks of 256 rows ----
        int c32 = t & 31, sub = t >> 5;     // 8 subwave groups
        int sh = (c32 & 7) * 4, widx = c32 >> 3;
        float acc[NHID_];
#pragma unroll
        for (int j = 0; j < NHID_; ++j) acc[j] = 0.f;
        for (int q = 0; q < 4; ++q) {
            __syncthreads();               // prev chunk's w1s reads done
            int wbase = (bc * 1024 + q * 256) * NHID_;
#pragma unroll
            for (int r = 0; r < 16; ++r) {
                int i = r * 256 + t;
                int gi = wbase + i;
                w1s[i] = (gi < 16000 * NHID_) ? W1[gi] : 0.f;
            }
            __syncthreads();
            const float4* w1v = (const float4*)w1s;
            int rl0 = q * 256 + sub * 32;
            // rows >= 16000: h==0 => xv=log(1)=0 and w1s staged 0 => no-op.
#pragma unroll 4
            for (int bl = 0; bl < 32; ++bl) {
                int rl = rl0 + bl;           // hist row 0..1023
                int rwc = sub * 32 + bl;     // w1s row 0..255
                unsigned int w = h[rl * 4 + widx];
                float xv = __shfl(logtab, (int)((w >> sh) & 0xfu));
                float4 wa = w1v[rwc * 4 + 0];
                float4 wb = w1v[rwc * 4 + 1];
                float4 wc = w1v[rwc * 4 + 2];
                float4 wd = w1v[rwc * 4 + 3];
                acc[0] = fmaf(xv, wa.x, acc[0]);  acc[1] = fmaf(xv, wa.y, acc[1]);
                acc[2] = fmaf(xv, wa.z, acc[2]);  acc[3] = fmaf(xv, wa.w, acc[3]);
                acc[4] = fmaf(xv, wb.x, acc[4]);  acc[5] = fmaf(xv, wb.y, acc[5]);
                acc[6] = fmaf(xv, wb.z, acc[6]);  acc[7] = fmaf(xv, wb.w, acc[7]);
                acc[8] = fmaf(xv, wc.x, acc[8]);  acc[9] = fmaf(xv, wc.y, acc[9]);
                acc[10] = fmaf(xv, wc.z, acc[10]); acc[11] = fmaf(xv, wc.w, acc[11]);
                acc[12] = fmaf(xv, wd.x, acc[12]); acc[13] = fmaf(xv, wd.y, acc[13]);
                acc[14] = fmaf(xv, wd.z, acc[14]); acc[15] = fmaf(xv, wd.w, acc[15]);
            }
        }
        __syncthreads();               // w1s dead; reuse as reduction sp
        float* sp = (float*)w1s;       // [8 subs][16 j][32 c] = 4096 floats
#pragma unroll
        for (int j = 0; j < NHID_; ++j) sp[sub * 512 + j * 32 + c32] = acc[j];
        __syncthreads();
        float dep = 0.f;
        for (int i = t; i < 512; i += 256) {
            int j = i >> 5, cc = i & 31;
            float v = 0.f;
#pragma unroll
            for (int s = 0; s < 8; ++s) v += sp[s * 512 + j * 32 + cc];
            // RETURNING atomic: vmcnt tracks completion at coherent point
            dep += atomicAdd(&hT[j * C_ + cg * 64 + half * 32 + cc], v);
        }
        asm volatile("" :: "v"(dep));  // keep returning form live
        __syncthreads();               // compiler drains vmcnt(0) here
        if (t == 0) atomicAdd(&done[1040], 1u);   // cutdone signal
    } else if (bid < 768) {
        // ---- per-bucket frag counts -> u8 ----
        int bk = bid - 512, cg = bk >> 4, gc = bk & 15;
        for (int i = t; i < 2048; i += 256) h[i] = 0;
        __syncthreads();
        unsigned int count = gcnt_f[bk];
        if (count > RCAP_FRAG) count = RCAP_FRAG;
        const unsigned short* e = entf + (size_t)bk * RCAP_FRAG;
#pragma unroll 4
        for (unsigned int p = t; p < count; p += 256) {
            unsigned int v = e[p];
            unsigned int g_lo = v & 63u;
            unsigned int c_lo = (v >> 6) & 63u;
            atomicAdd(&h[g_lo * 32 + (c_lo >> 1)], 1u << ((c_lo & 1) * 16));
        }
        __syncthreads();
        for (int i = t; i < 1024; i += 256) {
            int g_lo = i >> 4, wb = i & 15;
            unsigned int lo = h[g_lo * 32 + wb * 2];
            unsigned int hi = h[g_lo * 32 + wb * 2 + 1];
            unsigned int outv = (lo & 0xffu) | (((lo >> 16) & 0xffu) << 8)
                              | ((hi & 0xffu) << 16) | (((hi >> 16) & 0xffu) << 24);
            int g = gc * 64 + g_lo;
            if (g < G_)
                fragw[(unsigned)g * 256u + (unsigned)cg * 16u + wb] = outv;
        }
    } else {
        // ---- latent role (r22): spin until all 512 cut blocks signaled ----
        int lb = bid - 768;
        if (t == 0) {
            while (__hip_atomic_load(&done[1040], __ATOMIC_RELAXED,
                                     __HIP_MEMORY_SCOPE_AGENT) < 512u)
                __builtin_amdgcn_s_sleep(8);
        }
        __syncthreads();
        float* scs = (float*)w1s;          // overlay: 16 + 16 floats
        float* shs = ((float*)w1s) + 16;
        {   // per-block redundant BN stats (hT is L2-hot after spin)
            int j = t >> 4, cl = t & 15;
            double s1 = 0.0, s2 = 0.0;
#pragma unroll 8
            for (int k = 0; k < 64; ++k) {
                float v = hT[j * C_ + cl + k * 16];
                s1 += (double)v; s2 += (double)v * (double)v;
            }
#pragma unroll
            for (int m = 1; m < 16; m <<= 1) {
                s1 += __shfl_xor(s1, m);
                s2 += __shfl_xor(s2, m);
            }
            if (cl == 0) {
                double mean = s1 * (1.0 / C_);
                double var = s2 * (1.0 / C_) - mean * mean;
                float rstd = rsqrtf((float)var + 1e-5f);
                float sc = gamma[j] * rstd;
                scs[j] = sc;
                shs[j] = beta[j] - (float)mean * sc;
            }
        }
        __syncthreads();
        int idx = lb * 256 + t;
        float kl;
        {
            int c = idx / L_;
            int l = idx - c * L_;
            float hb[NHID_];
#pragma unroll
            for (int j = 0; j < NHID_; ++j) {
                float v = fmaf(hT[j * C_ + c], scs[j], shs[j]);
                hb[j] = v > 0.f ? v : 0.f;
            }
            float loc = b_loc[l], ls = b_scale[l];
#pragma unroll
            for (int j = 0; j < NHID_; ++j) {
                loc = fmaf(hb[j], W_loc[j * L_ + l], loc);
                ls  = fmaf(hb[j], W_scale[j * L_ + l], ls);
            }
            float qs = 0.1f * __expf(ls);
            float e = eps[idx];
            float lat = fmaf(qs, e, loc);
            latT[(size_t)l * C_ + c] = lat;           // normal stores: next
            latbf[c * 64 + l] = __float2bfloat16(lat);// dispatch sees them
            if (l < 14) latbf[c * 64 + 50 + l] = __float2bfloat16(0.f);
            float z = (lat - loc) / qs;
            kl = fmaf(-0.5f * lat, lat, fmaf(0.5f * z, z, __logf(qs)));
        }
        // per-wave reduce -> spread dacc atomics (no extra LDS)
#pragma unroll
        for (int m = 1; m < 64; m <<= 1) kl += __shfl_xor(kl, m);
        if ((t & 63) == 0)
            atomAddF64(&dacc[(lb * 4 + (t >> 6)) & 63],
                       (double)(-CELL_SCALE * kl));
    }
}

// --- 3. mixture (swapped-operand MFMA, lane-local softmax) + Poisson -------
// grid (1000, 2), 512 cells/block; merged layout [cg*2+half][bin][4w].
__global__ __launch_bounds__(256)
void mixpois_kernel(const __hip_bfloat16* __restrict__ latbf, // [1024][64]
                    const __hip_bfloat16* __restrict__ lwT,   // [1000][16][64]
                    const unsigned int* __restrict__ merged,  // [32][16000][4]
                    const float* __restrict__ baseline,       // [1000][16]
                    const float* __restrict__ latT,           // [50][1024]
                    const float* __restrict__ rw,             // [1000][50]
                    const float* __restrict__ rho_bias,
                    const int* __restrict__ libsize,
                    const unsigned char* __restrict__ fragb,  // [1000][1024]
                    double* __restrict__ dacc,                // [64]
                    unsigned int* __restrict__ done,          // zeroed
                    float* __restrict__ out) {
    int g = blockIdx.x;
    int y = blockIdx.y;
    int t = threadIdx.x;
    int lane = t & 63;
    int wv = t >> 6;
    int s16 = lane & 15;           // A row sel (comp) AND B col sel (cell)
    int quad = lane >> 4;
    const __hip_bfloat16* bb = lwT + (size_t)g * 1024 + s16 * 64 + quad * 8;
    short8 lw1 = *(const short8*)bb;
    short8 lw2 = *(const short8*)(bb + 32);
    const float4 bl4 = *(const float4*)(baseline + g * K_ + quad * 4);
    const unsigned int gb = ((unsigned)(g * K_ + quad * 4)) * 4u;  // bin base
    float partial = 0.f;
    int cwave = y * 512 + wv * 128;
#pragma unroll
    for (int mt = 0; mt < 8; ++mt) {
        int c0 = cwave + mt * 16;
        const __hip_bfloat16* aa = latbf + (size_t)(c0 + s16) * 64 + quad * 8;
        short8 la1 = *(const short8*)aa;
        short8 la2 = *(const short8*)(aa + 32);
        f32x4 d = {bl4.x, bl4.y, bl4.z, bl4.w};
        d = __builtin_amdgcn_mfma_f32_16x16x32_bf16(lw1, la1, d, 0, 0, 0);
        d = __builtin_amdgcn_mfma_f32_16x16x32_bf16(lw2, la2, d, 0, 0, 0);
        float m = fmaxf(fmaxf(d[0], d[1]), fmaxf(d[2], d[3]));
        m = fmaxf(m, __shfl_xor(m, 16));
        m = fmaxf(m, __shfl_xor(m, 32));
        float e0 = __expf(d[0] - m), e1 = __expf(d[1] - m);
        float e2 = __expf(d[2] - m), e3 = __expf(d[3] - m);
        float S = (e0 + e1) + (e2 + e3);
        S += __shfl_xor(S, 16);
        S += __shfl_xor(S, 32);
        float lse = m + __logf(S);
        int cp = c0 + s16;
        unsigned int base2 = ((unsigned)cp >> 5) * 64000u
                           + (((unsigned)cp & 31u) >> 3);
        int sb = (cp & 7) * 4;
#pragma unroll
        for (int r = 0; r < 4; ++r) {
            float cnt = (float)((merged[base2 + gb + r * 4u] >> sb) & 0xfu);
            partial = fmaf(cnt, d[r] - lse, partial);
        }
    }
    // ---- Poisson for the same 512-cell tile (2 cells/thread) ----
    float v;
    {
        const float* rwg = rw + (size_t)g * L_;   // hoists to SGPRs
        int cA = y * 512 + t, cB = cA + 256;
        float rhoA = 0.f, rhoB = 0.f;
#pragma unroll 10
        for (int l = 0; l < L_; ++l) {
            float wl = rwg[l];
            rhoA = fmaf(latT[l * C_ + cA], wl, rhoA);
            rhoB = fmaf(latT[l * C_ + cB], wl, rhoB);
        }
        unsigned int fcA = fragb[(size_t)g * C_ + cA];
        unsigned int fcB = fragb[(size_t)g * C_ + cB];
        float rb = rho_bias[g];
        float feA = rb * __expf(rhoA) * (float)libsize[cA];
        float feB = rb * __expf(rhoB) * (float)libsize[cB];
        float lfA = fmaf((float)fcA, __logf(feA), -feA) - LGT[fcA > 31u ? 31u : fcA];
        float lfB = fmaf((float)fcB, __logf(feB), -feB) - LGT[fcB > 31u ? 31u : fcB];
        v = fmaf(-CUT_SCALE, partial, -CELL_SCALE * (lfA + lfB));
    }
    float contrib = block_sum_256(v);
    // ---- fence-free fused final: atomic f64 accumulate + 2-level counter --
    __shared__ int lastflag;
    if (threadIdx.x == 0) {
        lastflag = 0;
        int slot = blockIdx.x & 63;
        double oldv = atomAddF64(&dacc[slot], (double)contrib);
        unsigned inc = 1u;
        float dep = (float)oldv;
        asm volatile("" : "+v"(inc) : "v"(dep));
        unsigned quota = ((slot < 40) ? 16u : 15u) * 2u;   // 1000 = 15*64+40
        if (atomicAdd(&done[slot * 16], inc) == quota - 1u) {
            if (atomicAdd(&done[1024], 1u) == 63u) lastflag = 1;
        }
    }
    __syncthreads();
    if (lastflag) {
        if (t < 64) {
            double dv = atomAddF64(&dacc[t], 0.0);
#pragma unroll
            for (int m = 1; m < 64; m <<= 1) dv += __shfl_xor(dv, m);
            if (t == 0)
                out[0] = (float)(dv - 138629436.11198905); // -12.5*4e6*log16
        }
    }
}

extern "C" void kernel_launch(void* const* d_in, const int* in_sizes, int n_in,
                              void* d_out, int out_size, void* d_ws, size_t ws_size,
                              hipStream_t stream) {
    const float* cut_coord = (const float*)d_in[0];
    const float* eps       = (const float*)d_in[1];
    const float* enc_W1    = (const float*)d_in[2];
    // d_in[3] = enc_b1 : cancels through BatchNorm, unused
    const float* bn_gamma  = (const float*)d_in[4];
    const float* bn_beta   = (const float*)d_in[5];
    const float* W_loc     = (const float*)d_in[6];
    const float* b_loc     = (const float*)d_in[7];
    const float* W_scale   = (const float*)d_in[8];
    const float* b_scale   = (const float*)d_in[9];
    const float* logit_w   = (const float*)d_in[10];
    const float* rho_w     = (const float*)d_in[11];
    const float* baseline  = (const float*)d_in[12];
    const float* rho_bias  = (const float*)d_in[13];
    const int* cut_cxg     = (const int*)d_in[14];
    const int* frag_ix     = (const int*)d_in[16];
    const int* libsize     = (const int*)d_in[19];

    int n_cuts  = in_sizes[0];
    int n_frags = in_sizes[16];

    char* ws = (char*)d_ws;
    unsigned int*   gcnt_c = (unsigned int*)(ws + GCNTC_OFF);
    unsigned int*   gcnt_f = (unsigned int*)(ws + GCNTF_OFF);
    unsigned int*   done   = (unsigned int*)(ws + DONE_OFF);
    double*         dacc   = (double*)(ws + DACC_OFF);
    float*          hT     = (float*)(ws + HT_OFF);
    __hip_bfloat16* latbf  = (__hip_bfloat16*)(ws + LATBF_OFF);
    __hip_bfloat16* lwT    = (__hip_bfloat16*)(ws + LWT_OFF);
    unsigned short* entc   = (unsigned short*)(ws + ENTC_OFF);
    unsigned short* entf   = (unsigned short*)(ws + ENTF_OFF);
    unsigned int*   merged = (unsigned int*)(ws + MERGED_OFF);
    unsigned int*   fragw  = (unsigned int*)(ws + FRAGU8_OFF);
    float*          latT   = (float*)(ws + LATT_OFF);
    float*          out    = (float*)d_out;

    int ncc = (n_cuts + CHUNK_ - 1) / CHUNK_;
    int ncf = (n_frags + CHUNK_ - 1) / CHUNK_;
    int nblk_part = ncc + ncf;

    hipMemsetAsync(ws, 0, ZERO_BYTES, stream);   // gcnt + done + dacc + hT

    part_kernel<<<nblk_part + 512, 256, 0, stream>>>(
        cut_cxg, cut_coord, frag_ix, gcnt_c, gcnt_f, entc, entf,
        logit_w, rho_w, lwT, dacc,
        n_cuts, n_frags, ncc, nblk_part);
    mid_kernel<<<968, 256, 0, stream>>>(
        gcnt_c, entc, gcnt_f, entf, enc_W1, merged, fragw, hT,
        bn_gamma, bn_beta, W_loc, b_loc, W_scale, b_scale, eps,
        latT, latbf, dacc, done);
    mixpois_kernel<<<dim3(G_, 2), 256, 0, stream>>>(
        latbf, lwT, merged, baseline, latT, rho_w, rho_bias, libsize,
        (const unsigned char*)fragw, dacc, done, out);
}

// Round 10
// 231.500 us; speedup vs baseline: 1.0278x; 1.0278x over previous
//
#include <hip/hip_runtime.h>
#include <hip/hip_bf16.h>
#include <math.h>

// ---------------------------------------------------------------------------
// VAE ELBO (chromatin VAE). Sizes fixed by the reference.
//
//  * NB_ENC == NB_DEC == 16, identical binning => ONE nibble histogram serves
//    both the encoder input (log1p counts) and the mixture likelihood.
//  * r3-r5: global per-record atomics too slow => two-phase LDS counting sort.
//  * r7: same-address atomics serialize ~16ns => spread slots / staggered.
//  * r12: hipLaunchCooperativeKernel DOES NOT RUN under this harness.
//  * r14: __threadfence = L2 wb/inv on 8 non-coherent XCD L2s => +138us. BAN.
//  * r15: fence-free cross-block dataflow: device-scope atomics at the
//    coherent point; explicit vmcnt drain orders signals. No fences.
//  * r16: swapped-operand MFMA => lane-local softmax; Poisson fused in.
//  * r17/r18: partition granularity + LDS/occupancy lessons (reverted).
//  * r19: mid split by CELLS (2 blocks/bucket, 32KB, grid 768). WIN.
//  * r20: part rank-from-count (no scatter atomics); mixpois (1000,2).
//  * r21: merged relaid [cg*2+half][bin][4w]; log1p table. 219.5us BEST.
//  * r22: latent fused into mid (spin role blocks) REGRESSED mid 38->64.6:
//    200 pollers x s_sleep(8) = ~1 atomic-load/ns on ONE coherent-point
//    address (~1 op/16ns capacity) => queue backup delayed cut blocks' own
//    coherent traffic (hT atomics). Spin STRUCTURE ok (passed), STORM bad.
//  * r23 (this round): same fusion, contention fixed: poll period 0.2us ->
//    1.7us (s_sleep(64), 8x fewer polls => ~0.2% of coherent capacity);
//    hT atomics non-returning + explicit per-wave s_waitcnt vmcnt(0) before
//    the barrier+signal (no returned-value round-trips). Falsification: if
//    total >= 219.5, revert to r21 and stop fusing.
// ---------------------------------------------------------------------------

#define G_      1000
#define C_      1024
#define L_      50
#define K_      16
#define NHID_   16
#define CUT_SCALE   12.5f          // N_TOTAL_CUTS / N_CUTS
#define CELL_SCALE  9.765625f      // N_TOTAL_CELLS / N_CELLS

#define CHUNK_    6144
#define RCAP_CUT  18432            // bucket capacity, cuts  (mean 16000)
#define RCAP_FRAG 9216             // bucket capacity, frags (mean 8000)

// ws layout (bytes); [0, ZERO_BYTES) memset per call (gcnt + done + dacc + hT).
#define GCNTC_OFF  0ull
#define GCNTF_OFF  1024ull
#define DONE_OFF   2048ull         // u32: 64 slots @16, lvl2 @[1024], cutdone @[1040]
#define DACC_OFF   6400ull         // f64[64] global ELBO accumulator slots
#define HT_OFF     6912ull         // f32 [16][1024] (atomic-accumulated by mid)
#define ZERO_BYTES 72448ull
#define LATBF_OFF  72448ull        // bf16 [1024][64]
#define LWT_OFF    203520ull       // bf16 [1000][16][64]
#define ENTC_OFF   2251520ull      // u16 [256][18432]
#define ENTF_OFF   11688704ull     // u16 [256][9216]
#define MERGED_OFF 16407296ull     // u32 [32 cg*2+half][16000 bin][4 w]
#define FRAGU8_OFF 24599296ull     // u8  [1000][1024]
#define LATT_OFF   25623296ull     // f32 [50][1024]
#define WS_NEED    25828096ull

typedef __attribute__((ext_vector_type(8))) short short8;
typedef __attribute__((ext_vector_type(4))) float f32x4;

__device__ __constant__ float LGT[32] = {   // log(n!)
    0.0f, 0.0f, 0.6931471805599453f, 1.791759469228055f, 3.1780538303479458f,
    4.787491742782046f, 6.579251212010101f, 8.525161361065415f,
    10.60460290274525f, 12.801827480081469f, 15.104412573075516f,
    17.502307845873887f, 19.987214495661885f, 22.552163853123425f,
    25.19122118273868f, 27.89927138384089f, 30.671860106080672f,
    33.50507345013689f, 36.39544520803305f, 39.339884187199495f,
    42.335616460753485f, 45.38013889847691f, 48.47118135183523f,
    51.60667556776438f, 54.78472939811232f, 58.00360522298052f,
    61.261701761002f, 64.55753862700633f, 67.88974313718154f,
    71.25703896716801f, 74.65823634883016f, 78.0922235533153f };

// f64 atomic add at the device coherent point (returns old value when used;
// NO fences anywhere).
__device__ __forceinline__ double atomAddF64(double* p, double v) {
    return __hip_atomic_fetch_add(p, v, __ATOMIC_RELAXED,
                                  __HIP_MEMORY_SCOPE_AGENT);
}

__device__ __forceinline__ float block_sum_256(float v) {
    __shared__ float sm[256];
    int t = threadIdx.x;
    __syncthreads();
    sm[t] = v;
    __syncthreads();
#pragma unroll
    for (int s = 128; s > 0; s >>= 1) {
        if (t < s) sm[t] += sm[t + s];
        __syncthreads();
    }
    return sm[0];
}

// --- 1. part: [0,nblk_part) radix partition (rank-from-count, no scatter
//        atomics) | [nblk_part, +256) lwprep | [+256, +512) wkl -------------
__global__ __launch_bounds__(256)
void part_kernel(const int* __restrict__ cut_ix,
                 const float* __restrict__ coord,
                 const int* __restrict__ frag_ix,
                 unsigned int* __restrict__ gcnt_c,
                 unsigned int* __restrict__ gcnt_f,
                 unsigned short* __restrict__ entc,
                 unsigned short* __restrict__ entf,
                 const float* __restrict__ lw,      // [1000][50][16]
                 const float* __restrict__ rw,      // [1000][50]
                 __hip_bfloat16* __restrict__ lwT,  // [1000][16][64]
                 double* __restrict__ dacc,         // [64]
                 int n_cuts, int n_frags, int ncc, int nblk_part) {
    int t = threadIdx.x;
    int bid = blockIdx.x;
    if (bid >= nblk_part) {
        int r = bid - nblk_part;
        if (r < 256) {
            // ---- lwprep: bf16 transpose [g][n][64], k-pads zeroed ----
            for (int g = r; g < G_; g += 256) {
                for (int i = t; i < L_ * K_; i += 256) {
                    float v = lw[(size_t)g * (L_ * K_) + i];
                    lwT[(size_t)g * 1024 + (i & 15) * 64 + (i >> 4)] =
                        __float2bfloat16(v);
                }
                for (int i = t; i < 16 * 14; i += 256) {
                    int n = i / 14, l = 50 + (i % 14);
                    lwT[(size_t)g * 1024 + n * 64 + l] = __float2bfloat16(0.f);
                }
            }
        } else {
            // ---- weight KL ----
            const int NTOT = G_ * L_ * K_ + G_ * L_;   // 850000
            int wb = r - 256;
            float s = 0.f;
            for (int i = wb * 256 + t; i < NTOT; i += 256 * 256) {
                float w = (i < G_ * L_ * K_) ? lw[i] : rw[i - G_ * L_ * K_];
                s += fmaf(-50.f * w, w, 1.3836465597893733f);
            }
            s = block_sum_256(s);
            if (t == 0) atomAddF64(&dacc[wb & 63], (double)(-s));
        }
        return;
    }
    // ---- radix partition, one 6144-record chunk per block ----
    __shared__ unsigned int cnt[256], excl[256], gbas[256];
    __shared__ unsigned short stage[CHUNK_];
    __shared__ unsigned char bkof[CHUNK_];
    bool isCut = (bid < ncc);
    int blk = isCut ? bid : bid - ncc;
    const int* idx = isCut ? cut_ix : frag_ix;
    int n = isCut ? n_cuts : n_frags;
    int rcap = isCut ? RCAP_CUT : RCAP_FRAG;
    unsigned int* gcount = isCut ? gcnt_c : gcnt_f;
    unsigned short* ent = isCut ? entc : entf;
    int i0 = blk * CHUNK_;
    cnt[t] = 0;
    // stage 24 records in registers: 6 int4 (+6 float4 for cuts), all in flight
    int4 I[6]; float4 X[6];
    unsigned int vm;
    bool full = (i0 + CHUNK_ <= n);
    if (full) {
        const int4* ip = (const int4*)(idx + i0);
#pragma unroll
        for (int k = 0; k < 6; ++k) I[k] = ip[k * 256 + t];
        if (isCut) {
            const float4* xp = (const float4*)(coord + i0);
#pragma unroll
            for (int k = 0; k < 6; ++k) X[k] = xp[k * 256 + t];
        }
        vm = 0xFFFFFFu;
    } else {
        vm = 0;
#pragma unroll
        for (int k = 0; k < 6; ++k) {
            int r0 = i0 + (k * 256 + t) * 4;
            int* Ii = (int*)&I[k]; float* Xi = (float*)&X[k];
#pragma unroll
            for (int u = 0; u < 4; ++u) {
                bool v = (r0 + u) < n;
                if (v) vm |= 1u << (k * 4 + u);
                Ii[u] = v ? idx[r0 + u] : 0;
                Xi[u] = (v && isCut) ? coord[r0 + u] : 0.f;
            }
        }
    }
    __syncthreads();
    // count phase: compute (e,bk) ONCE, rank = returning atomic; cache all
    // three in the now-dead I/X registers (r20).
#pragma unroll
    for (int k = 0; k < 6; ++k) {
        int* Ii = (int*)&I[k];
        unsigned int* Xi = (unsigned int*)&X[k];
#pragma unroll
        for (int u = 0; u < 4; ++u) {
            if (vm & (1u << (k * 4 + u))) {
                int ix = Ii[u];
                int c = ix / G_;
                int g = ix - c * G_;
                unsigned int bk; unsigned int e;
                if (isCut) {
                    float xf = ((const float*)Xi)[u];
                    int b = (int)(xf * 16.f); b = b > 15 ? 15 : b;
                    int bin = g * K_ + b;
                    bk = ((unsigned)(c >> 6) << 4) | ((unsigned)bin >> 10);
                    e = ((unsigned)(c & 63) << 10) | ((unsigned)bin & 1023u);
                } else {
                    bk = ((unsigned)(c >> 6) << 4) | ((unsigned)g >> 6);
                    e = ((unsigned)(c & 63) << 6) | ((unsigned)g & 63u);
                }
                unsigned int rank = atomicAdd(&cnt[bk], 1u);  // LDS, returning
                Ii[u] = (int)(e | (bk << 16));
                Xi[u] = rank;
            }
        }
    }
    __syncthreads();
    // exclusive prefix over 256 bucket counts, single wave, shfl scan
    if (t < 64) {
        unsigned int c0 = cnt[t * 4 + 0], c1 = cnt[t * 4 + 1];
        unsigned int c2 = cnt[t * 4 + 2], c3 = cnt[t * 4 + 3];
        unsigned int tot = c0 + c1 + c2 + c3;
        unsigned int run = tot;
#pragma unroll
        for (int o = 1; o < 64; o <<= 1) {
            unsigned int v = __shfl_up(run, o, 64);
            if (t >= o) run += v;
        }
        unsigned int base = run - tot;          // exclusive over 4-groups
        excl[t * 4 + 0] = base;
        excl[t * 4 + 1] = base + c0;
        excl[t * 4 + 2] = base + c0 + c1;
        excl[t * 4 + 3] = base + c0 + c1 + c2;
    }
    __syncthreads();
    gbas[t] = cnt[t] ? atomicAdd(&gcount[t], cnt[t]) : 0u;  // global reserve
    // scatter from registers: p = excl[bk] + rank — NO atomics (r20)
#pragma unroll
    for (int k = 0; k < 6; ++k) {
        const unsigned int* Ii = (const unsigned int*)&I[k];
        const unsigned int* Xi = (const unsigned int*)&X[k];
#pragma unroll
        for (int u = 0; u < 4; ++u) {
            if (vm & (1u << (k * 4 + u))) {
                unsigned int w = Ii[u];
                unsigned int bk = w >> 16;
                unsigned int p = excl[bk] + Xi[u];
                stage[p] = (unsigned short)(w & 0xffffu);
                bkof[p] = (unsigned char)bk;
            }
        }
    }
    __syncthreads();
    int total = n - i0; if (total > CHUNK_) total = CHUNK_;
    for (int p = t; p < total; p += 256) {
        unsigned int bk = bkof[p];
        unsigned int dst = gbas[bk] + (p - excl[bk]);
        if (dst < (unsigned)rcap)
            ent[(size_t)bk * rcap + dst] = stage[p];
    }
}

// --- 2. mid kernel: [0,512) cut hist+enc | [512,768) frag | [768,968)
//        latent (low-rate spin on cutdone) ----------------------------------
// All 968 blocks co-resident (32KB LDS => 5/CU = 1280 slots; launch_bounds
// guarantees >=4/CU = 1024) => spin is deadlock-free, no order assumption.
__global__ __launch_bounds__(256, 4)
void mid_kernel(const unsigned int* __restrict__ gcnt_c,
                const unsigned short* __restrict__ entc,
                const unsigned int* __restrict__ gcnt_f,
                const unsigned short* __restrict__ entf,
                const float* __restrict__ W1,        // [16000][16]
                unsigned int* __restrict__ merged,   // [32][16000][4]
                unsigned int* __restrict__ fragw,    // u8[1000][1024] as u32
                float* __restrict__ hT,              // [16][1024], pre-zeroed
                const float* __restrict__ gamma,
                const float* __restrict__ beta,
                const float* __restrict__ W_loc,     // [16][50]
                const float* __restrict__ b_loc,
                const float* __restrict__ W_scale,   // [16][50]
                const float* __restrict__ b_scale,
                const float* __restrict__ eps,       // [1024][50]
                float* __restrict__ latT,            // [50][1024]
                __hip_bfloat16* __restrict__ latbf,  // [1024][64]
                double* __restrict__ dacc,           // [64]
                unsigned int* __restrict__ done) {   // cutdone @ [1040]
    __shared__ unsigned int h[4096];   // 16 KB
    __shared__ float w1s[4096];        // 16 KB (role-local reuse)
    int t = threadIdx.x;
    int bid = blockIdx.x;
    if (bid < 512) {
        // ---- half-cell bucket: 1024 bins x 32 cells ----
        int bk = bid >> 1, half = bid & 1;
        int cg = bk >> 4, bc = bk & 15;
        for (int i = t; i < 4096; i += 256) h[i] = 0;
        // wave shfl log-table: lanes 0-15 hold log(1..16) (r22, zero LDS)
        float logtab = __logf((float)((t & 15) + 1));
        __syncthreads();
        unsigned int count = gcnt_c[bk];
        if (count > RCAP_CUT) count = RCAP_CUT;
        const unsigned int* e32 = (const unsigned int*)(entc + (size_t)bk * RCAP_CUT);
        unsigned int hsel = (unsigned)half << 5;
        unsigned int npair = count >> 1;
        for (unsigned int base = 0; base < npair; base += 1024) {
            unsigned int w[4]; bool val[4];
#pragma unroll
            for (int u = 0; u < 4; ++u) {
                unsigned int p = base + u * 256 + t;
                val[u] = (p < npair);
                w[u] = val[u] ? e32[p] : 0u;
            }
#pragma unroll
            for (int u = 0; u < 4; ++u) {
                if (val[u]) {
                    unsigned int v0 = w[u] & 0xffffu, v1 = w[u] >> 16;
                    unsigned int c0 = v0 >> 10, c1 = v1 >> 10;
                    if ((c0 & 32u) == hsel) {
                        unsigned int cc = c0 & 31u;
                        atomicAdd(&h[(v0 & 1023u) * 4 + (cc >> 3)],
                                  1u << ((cc & 7) * 4));
                    }
                    if ((c1 & 32u) == hsel) {
                        unsigned int cc = c1 & 31u;
                        atomicAdd(&h[(v1 & 1023u) * 4 + (cc >> 3)],
                                  1u << ((cc & 7) * 4));
                    }
                }
            }
        }
        if (t == 0 && (count & 1u)) {
            unsigned int v = ((const unsigned short*)e32)[count - 1];
            unsigned int c0 = v >> 10;
            if ((c0 & 32u) == hsel) {
                unsigned int cc = c0 & 31u;
                atomicAdd(&h[(v & 1023u) * 4 + (cc >> 3)], 1u << ((cc & 7) * 4));
            }
        }
        __syncthreads();
        // merged: ONE contiguous 16KB run per block (r21). bc==15 has only
        // 640 live bin rows (g*16+b <= 15999).
        {
            unsigned int mbase = ((unsigned)(cg * 2 + half)) * 64000u
                               + (unsigned)bc * 4096u;
            int lim = (bc == 15) ? 2560 : 4096;
            for (int i = t; i < lim; i += 256)
                merged[mbase + i] = h[i];
        }
        // ---- encoder: 1024 rows x 32 cells, 4 chunks of 256 rows ----
        int c32 = t & 31, sub = t >> 5;     // 8 subwave groups
        int sh = (c32 & 7) * 4, widx = c32 >> 3;
        float acc[NHID_];
#pragma unroll
        for (int j = 0; j < NHID_; ++j) acc[j] = 0.f;
        for (int q = 0; q < 4; ++q) {
            __syncthreads();               // prev chunk's w1s reads done
            int wbase = (bc * 1024 + q * 256) * NHID_;
#pragma unroll
            for (int r = 0; r < 16; ++r) {
                int i = r * 256 + t;
                int gi = wbase + i;
                w1s[i] = (gi < 16000 * NHID_) ? W1[gi] : 0.f;
            }
            __syncthreads();
            const float4* w1v = (const float4*)w1s;
            int rl0 = q * 256 + sub * 32;
            // rows >= 16000: h==0 => xv=log(1)=0 and w1s staged 0 => no-op.
#pragma unroll 4
            for (int bl = 0; bl < 32; ++bl) {
                int rl = rl0 + bl;           // hist row 0..1023
                int rwc = sub * 32 + bl;     // w1s row 0..255
                unsigned int w = h[rl * 4 + widx];
                float xv = __shfl(logtab, (int)((w >> sh) & 0xfu));
                float4 wa = w1v[rwc * 4 + 0];
                float4 wb = w1v[rwc * 4 + 1];
                float4 wc = w1v[rwc * 4 + 2];
                float4 wd = w1v[rwc * 4 + 3];
                acc[0] = fmaf(xv, wa.x, acc[0]);  acc[1] = fmaf(xv, wa.y, acc[1]);
                acc[2] = fmaf(xv, wa.z, acc[2]);  acc[3] = fmaf(xv, wa.w, acc[3]);
                acc[4] = fmaf(xv, wb.x, acc[4]);  acc[5] = fmaf(xv, wb.y, acc[5]);
                acc[6] = fmaf(xv, wb.z, acc[6]);  acc[7] = fmaf(xv, wb.w, acc[7]);
                acc[8] = fmaf(xv, wc.x, acc[8]);  acc[9] = fmaf(xv, wc.y, acc[9]);
                acc[10] = fmaf(xv, wc.z, acc[10]); acc[11] = fmaf(xv, wc.w, acc[11]);
                acc[12] = fmaf(xv, wd.x, acc[12]); acc[13] = fmaf(xv, wd.y, acc[13]);
                acc[14] = fmaf(xv, wd.z, acc[14]); acc[15] = fmaf(xv, wd.w, acc[15]);
            }
        }
        __syncthreads();               // w1s dead; reuse as reduction sp
        float* sp = (float*)w1s;       // [8 subs][16 j][32 c] = 4096 floats
#pragma unroll
        for (int j = 0; j < NHID_; ++j) sp[sub * 512 + j * 32 + c32] = acc[j];
        __syncthreads();
        for (int i = t; i < 512; i += 256) {
            int j = i >> 5, cc = i & 31;
            float v = 0.f;
#pragma unroll
            for (int s = 0; s < 8; ++s) v += sp[s * 512 + j * 32 + cc];
            atomicAdd(&hT[j * C_ + cg * 64 + half * 32 + cc], v);  // non-ret
        }
        // drain THIS wave's outstanding atomics before signaling (r23)
        asm volatile("s_waitcnt vmcnt(0)" ::: "memory");
        __syncthreads();               // all waves drained
        if (t == 0) atomicAdd(&done[1040], 1u);   // cutdone signal
    } else if (bid < 768) {
        // ---- per-bucket frag counts -> u8 ----
        int bk = bid - 512, cg = bk >> 4, gc = bk & 15;
        for (int i = t; i < 2048; i += 256) h[i] = 0;
        __syncthreads();
        unsigned int count = gcnt_f[bk];
        if (count > RCAP_FRAG) count = RCAP_FRAG;
        const unsigned short* e = entf + (size_t)bk * RCAP_FRAG;
#pragma unroll 4
        for (unsigned int p = t; p < count; p += 256) {
            unsigned int v = e[p];
            unsigned int g_lo = v & 63u;
            unsigned int c_lo = (v >> 6) & 63u;
            atomicAdd(&h[g_lo * 32 + (c_lo >> 1)], 1u << ((c_lo & 1) * 16));
        }
        __syncthreads();
        for (int i = t; i < 1024; i += 256) {
            int g_lo = i >> 4, wb = i & 15;
            unsigned int lo = h[g_lo * 32 + wb * 2];
            unsigned int hi = h[g_lo * 32 + wb * 2 + 1];
            unsigned int outv = (lo & 0xffu) | (((lo >> 16) & 0xffu) << 8)
                              | ((hi & 0xffu) << 16) | (((hi >> 16) & 0xffu) << 24);
            int g = gc * 64 + g_lo;
            if (g < G_)
                fragw[(unsigned)g * 256u + (unsigned)cg * 16u + wb] = outv;
        }
    } else {
        // ---- latent role: LOW-RATE spin until all 512 cut blocks done ----
        int lb = bid - 768;
        if (t == 0) {
            while (__hip_atomic_load(&done[1040], __ATOMIC_RELAXED,
                                     __HIP_MEMORY_SCOPE_AGENT) < 512u)
                __builtin_amdgcn_s_sleep(64);   // ~1.7us poll period (r23)
        }
        __syncthreads();
        float* scs = (float*)w1s;          // overlay: 16 + 16 floats
        float* shs = ((float*)w1s) + 16;
        {   // per-block redundant BN stats (hT is L2-hot after spin)
            int j = t >> 4, cl = t & 15;
            double s1 = 0.0, s2 = 0.0;
#pragma unroll 8
            for (int k = 0; k < 64; ++k) {
                float v = hT[j * C_ + cl + k * 16];
                s1 += (double)v; s2 += (double)v * (double)v;
            }
#pragma unroll
            for (int m = 1; m < 16; m <<= 1) {
                s1 += __shfl_xor(s1, m);
                s2 += __shfl_xor(s2, m);
            }
            if (cl == 0) {
                double mean = s1 * (1.0 / C_);
                double var = s2 * (1.0 / C_) - mean * mean;
                float rstd = rsqrtf((float)var + 1e-5f);
                float sc = gamma[j] * rstd;
                scs[j] = sc;
                shs[j] = beta[j] - (float)mean * sc;
            }
        }
        __syncthreads();
        int idx = lb * 256 + t;
        float kl;
        {
            int c = idx / L_;
            int l = idx - c * L_;
            float hb[NHID_];
#pragma unroll
            for (int j = 0; j < NHID_; ++j) {
                float v = fmaf(hT[j * C_ + c], scs[j], shs[j]);
                hb[j] = v > 0.f ? v : 0.f;
            }
            float loc = b_loc[l], ls = b_scale[l];
#pragma unroll
            for (int j = 0; j < NHID_; ++j) {
                loc = fmaf(hb[j], W_loc[j * L_ + l], loc);
                ls  = fmaf(hb[j], W_scale[j * L_ + l], ls);
            }
            float qs = 0.1f * __expf(ls);
            float e = eps[idx];
            float lat = fmaf(qs, e, loc);
            latT[(size_t)l * C_ + c] = lat;           // normal stores: next
            latbf[c * 64 + l] = __float2bfloat16(lat);// dispatch sees them
            if (l < 14) latbf[c * 64 + 50 + l] = __float2bfloat16(0.f);
            float z = (lat - loc) / qs;
            kl = fmaf(-0.5f * lat, lat, fmaf(0.5f * z, z, __logf(qs)));
        }
        // per-wave reduce -> spread dacc atomics (no extra LDS)
#pragma unroll
        for (int m = 1; m < 64; m <<= 1) kl += __shfl_xor(kl, m);
        if ((t & 63) == 0)
            atomAddF64(&dacc[(lb * 4 + (t >> 6)) & 63],
                       (double)(-CELL_SCALE * kl));
    }
}

// --- 3. mixture (swapped-operand MFMA, lane-local softmax) + Poisson -------
// grid (1000, 2), 512 cells/block; merged layout [cg*2+half][bin][4w].
__global__ __launch_bounds__(256)
void mixpois_kernel(const __hip_bfloat16* __restrict__ latbf, // [1024][64]
                    const __hip_bfloat16* __restrict__ lwT,   // [1000][16][64]
                    const unsigned int* __restrict__ merged,  // [32][16000][4]
                    const float* __restrict__ baseline,       // [1000][16]
                    const float* __restrict__ latT,           // [50][1024]
                    const float* __restrict__ rw,             // [1000][50]
                    const float* __restrict__ rho_bias,
                    const int* __restrict__ libsize,
                    const unsigned char* __restrict__ fragb,  // [1000][1024]
                    double* __restrict__ dacc,                // [64]
                    unsigned int* __restrict__ done,          // zeroed
                    float* __restrict__ out) {
    int g = blockIdx.x;
    int y = blockIdx.y;
    int t = threadIdx.x;
    int lane = t & 63;
    int wv = t >> 6;
    int s16 = lane & 15;           // A row sel (comp) AND B col sel (cell)
    int quad = lane >> 4;
    const __hip_bfloat16* bb = lwT + (size_t)g * 1024 + s16 * 64 + quad * 8;
    short8 lw1 = *(const short8*)bb;
    short8 lw2 = *(const short8*)(bb + 32);
    const float4 bl4 = *(const float4*)(baseline + g * K_ + quad * 4);
    const unsigned int gb = ((unsigned)(g * K_ + quad * 4)) * 4u;  // bin base
    float partial = 0.f;
    int cwave = y * 512 + wv * 128;
#pragma unroll
    for (int mt = 0; mt < 8; ++mt) {
        int c0 = cwave + mt * 16;
        const __hip_bfloat16* aa = latbf + (size_t)(c0 + s16) * 64 + quad * 8;
        short8 la1 = *(const short8*)aa;
        short8 la2 = *(const short8*)(aa + 32);
        f32x4 d = {bl4.x, bl4.y, bl4.z, bl4.w};
        d = __builtin_amdgcn_mfma_f32_16x16x32_bf16(lw1, la1, d, 0, 0, 0);
        d = __builtin_amdgcn_mfma_f32_16x16x32_bf16(lw2, la2, d, 0, 0, 0);
        float m = fmaxf(fmaxf(d[0], d[1]), fmaxf(d[2], d[3]));
        m = fmaxf(m, __shfl_xor(m, 16));
        m = fmaxf(m, __shfl_xor(m, 32));
        float e0 = __expf(d[0] - m), e1 = __expf(d[1] - m);
        float e2 = __expf(d[2] - m), e3 = __expf(d[3] - m);
        float S = (e0 + e1) + (e2 + e3);
        S += __shfl_xor(S, 16);
        S += __shfl_xor(S, 32);
        float lse = m + __logf(S);
        int cp = c0 + s16;
        unsigned int base2 = ((unsigned)cp >> 5) * 64000u
                           + (((unsigned)cp & 31u) >> 3);
        int sb = (cp & 7) * 4;
#pragma unroll
        for (int r = 0; r < 4; ++r) {
            float cnt = (float)((merged[base2 + gb + r * 4u] >> sb) & 0xfu);
            partial = fmaf(cnt, d[r] - lse, partial);
        }
    }
    // ---- Poisson for the same 512-cell tile (2 cells/thread) ----
    float v;
    {
        const float* rwg = rw + (size_t)g * L_;   // hoists to SGPRs
        int cA = y * 512 + t, cB = cA + 256;
        float rhoA = 0.f, rhoB = 0.f;
#pragma unroll 10
        for (int l = 0; l < L_; ++l) {
            float wl = rwg[l];
            rhoA = fmaf(latT[l * C_ + cA], wl, rhoA);
            rhoB = fmaf(latT[l * C_ + cB], wl, rhoB);
        }
        unsigned int fcA = fragb[(size_t)g * C_ + cA];
        unsigned int fcB = fragb[(size_t)g * C_ + cB];
        float rb = rho_bias[g];
        float feA = rb * __expf(rhoA) * (float)libsize[cA];
        float feB = rb * __expf(rhoB) * (float)libsize[cB];
        float lfA = fmaf((float)fcA, __logf(feA), -feA) - LGT[fcA > 31u ? 31u : fcA];
        float lfB = fmaf((float)fcB, __logf(feB), -feB) - LGT[fcB > 31u ? 31u : fcB];
        v = fmaf(-CUT_SCALE, partial, -CELL_SCALE * (lfA + lfB));
    }
    float contrib = block_sum_256(v);
    // ---- fence-free fused final: atomic f64 accumulate + 2-level counter --
    __shared__ int lastflag;
    if (threadIdx.x == 0) {
        lastflag = 0;
        int slot = blockIdx.x & 63;
        double oldv = atomAddF64(&dacc[slot], (double)contrib);
        unsigned inc = 1u;
        float dep = (float)oldv;
        asm volatile("" : "+v"(inc) : "v"(dep));
        unsigned quota = ((slot < 40) ? 16u : 15u) * 2u;   // 1000 = 15*64+40
        if (atomicAdd(&done[slot * 16], inc) == quota - 1u) {
            if (atomicAdd(&done[1024], 1u) == 63u) lastflag = 1;
        }
    }
    __syncthreads();
    if (lastflag) {
        if (t < 64) {
            double dv = atomAddF64(&dacc[t], 0.0);
#pragma unroll
            for (int m = 1; m < 64; m <<= 1) dv += __shfl_xor(dv, m);
            if (t == 0)
                out[0] = (float)(dv - 138629436.11198905); // -12.5*4e6*log16
        }
    }
}

extern "C" void kernel_launch(void* const* d_in, const int* in_sizes, int n_in,
                              void* d_out, int out_size, void* d_ws, size_t ws_size,
                              hipStream_t stream) {
    const float* cut_coord = (const float*)d_in[0];
    const float* eps       = (const float*)d_in[1];
    const float* enc_W1    = (const float*)d_in[2];
    // d_in[3] = enc_b1 : cancels through BatchNorm, unused
    const float* bn_gamma  = (const float*)d_in[4];
    const float* bn_beta   = (const float*)d_in[5];
    const float* W_loc     = (const float*)d_in[6];
    const float* b_loc     = (const float*)d_in[7];
    const float* W_scale   = (const float*)d_in[8];
    const float* b_scale   = (const float*)d_in[9];
    const float* logit_w   = (const float*)d_in[10];
    const float* rho_w     = (const float*)d_in[11];
    const float* baseline  = (const float*)d_in[12];
    const float* rho_bias  = (const float*)d_in[13];
    const int* cut_cxg     = (const int*)d_in[14];
    const int* frag_ix     = (const int*)d_in[16];
    const int* libsize     = (const int*)d_in[19];

    int n_cuts  = in_sizes[0];
    int n_frags = in_sizes[16];

    char* ws = (char*)d_ws;
    unsigned int*   gcnt_c = (unsigned int*)(ws + GCNTC_OFF);
    unsigned int*   gcnt_f = (unsigned int*)(ws + GCNTF_OFF);
    unsigned int*   done   = (unsigned int*)(ws + DONE_OFF);
    double*         dacc   = (double*)(ws + DACC_OFF);
    float*          hT     = (float*)(ws + HT_OFF);
    __hip_bfloat16* latbf  = (__hip_bfloat16*)(ws + LATBF_OFF);
    __hip_bfloat16* lwT    = (__hip_bfloat16*)(ws + LWT_OFF);
    unsigned short* entc   = (unsigned short*)(ws + ENTC_OFF);
    unsigned short* entf   = (unsigned short*)(ws + ENTF_OFF);
    unsigned int*   merged = (unsigned int*)(ws + MERGED_OFF);
    unsigned int*   fragw  = (unsigned int*)(ws + FRAGU8_OFF);
    float*          latT   = (float*)(ws + LATT_OFF);
    float*          out    = (float*)d_out;

    int ncc = (n_cuts + CHUNK_ - 1) / CHUNK_;
    int ncf = (n_frags + CHUNK_ - 1) / CHUNK_;
    int nblk_part = ncc + ncf;

    hipMemsetAsync(ws, 0, ZERO_BYTES, stream);   // gcnt + done + dacc + hT

    part_kernel<<<nblk_part + 512, 256, 0, stream>>>(
        cut_cxg, cut_coord, frag_ix, gcnt_c, gcnt_f, entc, entf,
        logit_w, rho_w, lwT, dacc,
        n_cuts, n_frags, ncc, nblk_part);
    mid_kernel<<<968, 256, 0, stream>>>(
        gcnt_c, entc, gcnt_f, entf, enc_W1, merged, fragw, hT,
        bn_gamma, bn_beta, W_loc, b_loc, W_scale, b_scale, eps,
        latT, latbf, dacc, done);
    mixpois_kernel<<<dim3(G_, 2), 256, 0, stream>>>(
        latbf, lwT, merged, baseline, latT, rho_w, rho_bias, libsize,
        (const unsigned char*)fragw, dacc, done, out);
}

// Round 11
// 218.749 us; speedup vs baseline: 1.0877x; 1.0583x over previous
//
#include <hip/hip_runtime.h>
#include <hip/hip_bf16.h>
#include <math.h>

// ---------------------------------------------------------------------------
// VAE ELBO (chromatin VAE). Sizes fixed by the reference.
//
//  * NB_ENC == NB_DEC == 16, identical binning => ONE nibble histogram serves
//    both the encoder input (log1p counts) and the mixture likelihood.
//  * r3-r5: global per-record atomics too slow => two-phase LDS counting sort.
//  * r7: same-address atomics serialize ~16ns => spread slots / staggered.
//  * r12: hipLaunchCooperativeKernel DOES NOT RUN under this harness.
//  * r14: __threadfence = L2 wb/inv on 8 non-coherent XCD L2s => +138us. BAN.
//  * r15: fence-free tail: f64 atomics into dacc[64]; returning-atomic
//    data-dep orders done-counter.
//  * r16: swapped-operand MFMA => lane-local softmax; Poisson fused in.
//  * r17/r18: partition granularity + LDS/occupancy lessons (reverted).
//  * r19: mid split by CELLS (2 blocks/bucket, 32KB, grid 768). WIN.
//  * r20: part rank-from-count (no scatter atomics); mixpois (1000,2).
//  * r21: merged relaid [cg*2+half][bin][4w]; log1p LUT. 219.5us BEST.
//  * r22/r23: latent-into-mid spin fusion REGRESSED (237.9 / 231.5).
//    Root cause beyond poll-storm: 200 spinner blocks hold ~20% of
//    resident slots+LDS for the whole cut phase doing nothing, then
//    latent serializes at the tail anyway. Resource-holding spin in a
//    fully-resident grid is a structural loss. REVERTED per the
//    pre-committed falsification rule; NO MORE FUSING.
//  * r24 (this round): r21 restored + ONE change: mixpois prefetches all
//    32 merged words (addresses known at entry, independent of MFMA)
//    before the MFMA loop — removes ~8 exposed ~200cy L2 latencies per
//    thread. VGPR 28->~64, still ample occupancy.
// ---------------------------------------------------------------------------

#define G_      1000
#define C_      1024
#define L_      50
#define K_      16
#define NHID_   16
#define CUT_SCALE   12.5f          // N_TOTAL_CUTS / N_CUTS
#define CELL_SCALE  9.765625f      // N_TOTAL_CELLS / N_CELLS

#define CHUNK_    6144
#define RCAP_CUT  18432            // bucket capacity, cuts  (mean 16000)
#define RCAP_FRAG 9216             // bucket capacity, frags (mean 8000)

// ws layout (bytes); [0, ZERO_BYTES) memset per call (gcnt + done + dacc + hT).
#define GCNTC_OFF  0ull
#define GCNTF_OFF  1024ull
#define DONE_OFF   2048ull         // u32: 64 slots @ stride 16 u32, lvl2 @ [1024]
#define DACC_OFF   6400ull         // f64[64] global ELBO accumulator slots
#define HT_OFF     6912ull         // f32 [16][1024] (atomic-accumulated by mid)
#define ZERO_BYTES 72448ull
#define LATBF_OFF  72448ull        // bf16 [1024][64]
#define LWT_OFF    203520ull       // bf16 [1000][16][64]
#define ENTC_OFF   2251520ull      // u16 [256][18432]
#define ENTF_OFF   11688704ull     // u16 [256][9216]
#define MERGED_OFF 16407296ull     // u32 [32 cg*2+half][16000 bin][4 w]
#define FRAGU8_OFF 24599296ull     // u8  [1000][1024]
#define LATT_OFF   25623296ull     // f32 [50][1024]
#define WS_NEED    25828096ull

typedef __attribute__((ext_vector_type(8))) short short8;
typedef __attribute__((ext_vector_type(4))) float f32x4;

__device__ __constant__ float LGT[32] = {   // log(n!)
    0.0f, 0.0f, 0.6931471805599453f, 1.791759469228055f, 3.1780538303479458f,
    4.787491742782046f, 6.579251212010101f, 8.525161361065415f,
    10.60460290274525f, 12.801827480081469f, 15.104412573075516f,
    17.502307845873887f, 19.987214495661885f, 22.552163853123425f,
    25.19122118273868f, 27.89927138384089f, 30.671860106080672f,
    33.50507345013689f, 36.39544520803305f, 39.339884187199495f,
    42.335616460753485f, 45.38013889847691f, 48.47118135183523f,
    51.60667556776438f, 54.78472939811232f, 58.00360522298052f,
    61.261701761002f, 64.55753862700633f, 67.88974313718154f,
    71.25703896716801f, 74.65823634883016f, 78.0922235533153f };

// f64 atomic add at the device coherent point (returns old value; the return
// is used to fabricate ordering dependencies — NO fences anywhere).
__device__ __forceinline__ double atomAddF64(double* p, double v) {
    return __hip_atomic_fetch_add(p, v, __ATOMIC_RELAXED,
                                  __HIP_MEMORY_SCOPE_AGENT);
}

__device__ __forceinline__ float block_sum_256(float v) {
    __shared__ float sm[256];
    int t = threadIdx.x;
    __syncthreads();
    sm[t] = v;
    __syncthreads();
#pragma unroll
    for (int s = 128; s > 0; s >>= 1) {
        if (t < s) sm[t] += sm[t + s];
        __syncthreads();
    }
    return sm[0];
}

// --- 1. part: [0,nblk_part) radix partition (rank-from-count, no scatter
//        atomics) | [nblk_part, +256) lwprep | [+256, +512) wkl -------------
__global__ __launch_bounds__(256)
void part_kernel(const int* __restrict__ cut_ix,
                 const float* __restrict__ coord,
                 const int* __restrict__ frag_ix,
                 unsigned int* __restrict__ gcnt_c,
                 unsigned int* __restrict__ gcnt_f,
                 unsigned short* __restrict__ entc,
                 unsigned short* __restrict__ entf,
                 const float* __restrict__ lw,      // [1000][50][16]
                 const float* __restrict__ rw,      // [1000][50]
                 __hip_bfloat16* __restrict__ lwT,  // [1000][16][64]
                 double* __restrict__ dacc,         // [64]
                 int n_cuts, int n_frags, int ncc, int nblk_part) {
    int t = threadIdx.x;
    int bid = blockIdx.x;
    if (bid >= nblk_part) {
        int r = bid - nblk_part;
        if (r < 256) {
            // ---- lwprep: bf16 transpose [g][n][64], k-pads zeroed ----
            for (int g = r; g < G_; g += 256) {
                for (int i = t; i < L_ * K_; i += 256) {
                    float v = lw[(size_t)g * (L_ * K_) + i];
                    lwT[(size_t)g * 1024 + (i & 15) * 64 + (i >> 4)] =
                        __float2bfloat16(v);
                }
                for (int i = t; i < 16 * 14; i += 256) {
                    int n = i / 14, l = 50 + (i % 14);
                    lwT[(size_t)g * 1024 + n * 64 + l] = __float2bfloat16(0.f);
                }
            }
        } else {
            // ---- weight KL ----
            const int NTOT = G_ * L_ * K_ + G_ * L_;   // 850000
            int wb = r - 256;
            float s = 0.f;
            for (int i = wb * 256 + t; i < NTOT; i += 256 * 256) {
                float w = (i < G_ * L_ * K_) ? lw[i] : rw[i - G_ * L_ * K_];
                s += fmaf(-50.f * w, w, 1.3836465597893733f);
            }
            s = block_sum_256(s);
            if (t == 0) atomAddF64(&dacc[wb & 63], (double)(-s));
        }
        return;
    }
    // ---- radix partition, one 6144-record chunk per block ----
    __shared__ unsigned int cnt[256], excl[256], gbas[256];
    __shared__ unsigned short stage[CHUNK_];
    __shared__ unsigned char bkof[CHUNK_];
    bool isCut = (bid < ncc);
    int blk = isCut ? bid : bid - ncc;
    const int* idx = isCut ? cut_ix : frag_ix;
    int n = isCut ? n_cuts : n_frags;
    int rcap = isCut ? RCAP_CUT : RCAP_FRAG;
    unsigned int* gcount = isCut ? gcnt_c : gcnt_f;
    unsigned short* ent = isCut ? entc : entf;
    int i0 = blk * CHUNK_;
    cnt[t] = 0;
    // stage 24 records in registers: 6 int4 (+6 float4 for cuts), all in flight
    int4 I[6]; float4 X[6];
    unsigned int vm;
    bool full = (i0 + CHUNK_ <= n);
    if (full) {
        const int4* ip = (const int4*)(idx + i0);
#pragma unroll
        for (int k = 0; k < 6; ++k) I[k] = ip[k * 256 + t];
        if (isCut) {
            const float4* xp = (const float4*)(coord + i0);
#pragma unroll
            for (int k = 0; k < 6; ++k) X[k] = xp[k * 256 + t];
        }
        vm = 0xFFFFFFu;
    } else {
        vm = 0;
#pragma unroll
        for (int k = 0; k < 6; ++k) {
            int r0 = i0 + (k * 256 + t) * 4;
            int* Ii = (int*)&I[k]; float* Xi = (float*)&X[k];
#pragma unroll
            for (int u = 0; u < 4; ++u) {
                bool v = (r0 + u) < n;
                if (v) vm |= 1u << (k * 4 + u);
                Ii[u] = v ? idx[r0 + u] : 0;
                Xi[u] = (v && isCut) ? coord[r0 + u] : 0.f;
            }
        }
    }
    __syncthreads();
    // count phase: compute (e,bk) ONCE, rank = returning atomic; cache all
    // three in the now-dead I/X registers (r20).
#pragma unroll
    for (int k = 0; k < 6; ++k) {
        int* Ii = (int*)&I[k];
        unsigned int* Xi = (unsigned int*)&X[k];
#pragma unroll
        for (int u = 0; u < 4; ++u) {
            if (vm & (1u << (k * 4 + u))) {
                int ix = Ii[u];
                int c = ix / G_;
                int g = ix - c * G_;
                unsigned int bk; unsigned int e;
                if (isCut) {
                    float xf = ((const float*)Xi)[u];
                    int b = (int)(xf * 16.f); b = b > 15 ? 15 : b;
                    int bin = g * K_ + b;
                    bk = ((unsigned)(c >> 6) << 4) | ((unsigned)bin >> 10);
                    e = ((unsigned)(c & 63) << 10) | ((unsigned)bin & 1023u);
                } else {
                    bk = ((unsigned)(c >> 6) << 4) | ((unsigned)g >> 6);
                    e = ((unsigned)(c & 63) << 6) | ((unsigned)g & 63u);
                }
                unsigned int rank = atomicAdd(&cnt[bk], 1u);  // LDS, returning
                Ii[u] = (int)(e | (bk << 16));
                Xi[u] = rank;
            }
        }
    }
    __syncthreads();
    // exclusive prefix over 256 bucket counts, single wave, shfl scan
    if (t < 64) {
        unsigned int c0 = cnt[t * 4 + 0], c1 = cnt[t * 4 + 1];
        unsigned int c2 = cnt[t * 4 + 2], c3 = cnt[t * 4 + 3];
        unsigned int tot = c0 + c1 + c2 + c3;
        unsigned int run = tot;
#pragma unroll
        for (int o = 1; o < 64; o <<= 1) {
            unsigned int v = __shfl_up(run, o, 64);
            if (t >= o) run += v;
        }
        unsigned int base = run - tot;          // exclusive over 4-groups
        excl[t * 4 + 0] = base;
        excl[t * 4 + 1] = base + c0;
        excl[t * 4 + 2] = base + c0 + c1;
        excl[t * 4 + 3] = base + c0 + c1 + c2;
    }
    __syncthreads();
    gbas[t] = cnt[t] ? atomicAdd(&gcount[t], cnt[t]) : 0u;  // global reserve
    // scatter from registers: p = excl[bk] + rank — NO atomics (r20)
#pragma unroll
    for (int k = 0; k < 6; ++k) {
        const unsigned int* Ii = (const unsigned int*)&I[k];
        const unsigned int* Xi = (const unsigned int*)&X[k];
#pragma unroll
        for (int u = 0; u < 4; ++u) {
            if (vm & (1u << (k * 4 + u))) {
                unsigned int w = Ii[u];
                unsigned int bk = w >> 16;
                unsigned int p = excl[bk] + Xi[u];
                stage[p] = (unsigned short)(w & 0xffffu);
                bkof[p] = (unsigned char)bk;
            }
        }
    }
    __syncthreads();
    int total = n - i0; if (total > CHUNK_) total = CHUNK_;
    for (int p = t; p < total; p += 256) {
        unsigned int bk = bkof[p];
        unsigned int dst = gbas[bk] + (p - excl[bk]);
        if (dst < (unsigned)rcap)
            ent[(size_t)bk * rcap + dst] = stage[p];
    }
}

// --- 2. mid kernel: [0,512) half-cell bucket hist+enc | [512,768) frag -----
// r19: 2 blocks/bucket by CELLS. r21: merged write is one contiguous 16KB
// run per block (no sector RMW); log1p via 16-entry LDS LUT.
__global__ __launch_bounds__(256)
void mid_kernel(const unsigned int* __restrict__ gcnt_c,
                const unsigned short* __restrict__ entc,
                const unsigned int* __restrict__ gcnt_f,
                const unsigned short* __restrict__ entf,
                const float* __restrict__ W1,        // [16000][16]
                unsigned int* __restrict__ merged,   // [32][16000][4]
                unsigned int* __restrict__ fragw,    // u8[1000][1024] as u32
                float* __restrict__ hT) {            // [16][1024], pre-zeroed
    __shared__ unsigned int h[4096];   // 16 KB: [1024 bins][4w of 8 cells]
    __shared__ float w1s[4096];        // 16 KB W1 chunk stage / reduction sp
    __shared__ float lgl[16];          // log1p LUT (counts are 4-bit)
    int t = threadIdx.x;
    int bid = blockIdx.x;
    if (bid < 512) {
        // ---- half-cell bucket: 1024 bins x 32 cells ----
        int bk = bid >> 1, half = bid & 1;
        int cg = bk >> 4, bc = bk & 15;
        for (int i = t; i < 4096; i += 256) h[i] = 0;
        if (t < 16) lgl[t] = __logf((float)(t + 1));
        __syncthreads();
        unsigned int count = gcnt_c[bk];
        if (count > RCAP_CUT) count = RCAP_CUT;
        const unsigned int* e32 = (const unsigned int*)(entc + (size_t)bk * RCAP_CUT);
        unsigned int hsel = (unsigned)half << 5;
        unsigned int npair = count >> 1;
        for (unsigned int base = 0; base < npair; base += 1024) {
            unsigned int w[4]; bool val[4];
#pragma unroll
            for (int u = 0; u < 4; ++u) {
                unsigned int p = base + u * 256 + t;
                val[u] = (p < npair);
                w[u] = val[u] ? e32[p] : 0u;
            }
#pragma unroll
            for (int u = 0; u < 4; ++u) {
                if (val[u]) {
                    unsigned int v0 = w[u] & 0xffffu, v1 = w[u] >> 16;
                    unsigned int c0 = v0 >> 10, c1 = v1 >> 10;
                    if ((c0 & 32u) == hsel) {
                        unsigned int cc = c0 & 31u;
                        atomicAdd(&h[(v0 & 1023u) * 4 + (cc >> 3)],
                                  1u << ((cc & 7) * 4));
                    }
                    if ((c1 & 32u) == hsel) {
                        unsigned int cc = c1 & 31u;
                        atomicAdd(&h[(v1 & 1023u) * 4 + (cc >> 3)],
                                  1u << ((cc & 7) * 4));
                    }
                }
            }
        }
        if (t == 0 && (count & 1u)) {
            unsigned int v = ((const unsigned short*)e32)[count - 1];
            unsigned int c0 = v >> 10;
            if ((c0 & 32u) == hsel) {
                unsigned int cc = c0 & 31u;
                atomicAdd(&h[(v & 1023u) * 4 + (cc >> 3)], 1u << ((cc & 7) * 4));
            }
        }
        __syncthreads();
        // merged: ONE contiguous 16KB run per block (r21). bc==15 has only
        // 640 live bin rows (g*16+b <= 15999).
        {
            unsigned int mbase = ((unsigned)(cg * 2 + half)) * 64000u
                               + (unsigned)bc * 4096u;
            int lim = (bc == 15) ? 2560 : 4096;
            for (int i = t; i < lim; i += 256)
                merged[mbase + i] = h[i];
        }
        // ---- encoder: 1024 rows x 32 cells, 4 chunks of 256 rows ----
        int c32 = t & 31, sub = t >> 5;     // 8 subwave groups
        int sh = (c32 & 7) * 4, widx = c32 >> 3;
        float acc[NHID_];
#pragma unroll
        for (int j = 0; j < NHID_; ++j) acc[j] = 0.f;
        for (int q = 0; q < 4; ++q) {
            __syncthreads();               // prev chunk's w1s reads done
            int wbase = (bc * 1024 + q * 256) * NHID_;
#pragma unroll
            for (int r = 0; r < 16; ++r) {
                int i = r * 256 + t;
                int gi = wbase + i;
                w1s[i] = (gi < 16000 * NHID_) ? W1[gi] : 0.f;
            }
            __syncthreads();
            const float4* w1v = (const float4*)w1s;
            int rl0 = q * 256 + sub * 32;
            // rows >= 16000: h==0 => xv=log(1)=0 and w1s staged 0 => no-op.
#pragma unroll 4
            for (int bl = 0; bl < 32; ++bl) {
                int rl = rl0 + bl;           // hist row 0..1023
                int rwc = sub * 32 + bl;     // w1s row 0..255
                unsigned int w = h[rl * 4 + widx];
                float xv = lgl[(w >> sh) & 0xfu];   // r21: LUT, not __logf
                float4 wa = w1v[rwc * 4 + 0];
                float4 wb = w1v[rwc * 4 + 1];
                float4 wc = w1v[rwc * 4 + 2];
                float4 wd = w1v[rwc * 4 + 3];
                acc[0] = fmaf(xv, wa.x, acc[0]);  acc[1] = fmaf(xv, wa.y, acc[1]);
                acc[2] = fmaf(xv, wa.z, acc[2]);  acc[3] = fmaf(xv, wa.w, acc[3]);
                acc[4] = fmaf(xv, wb.x, acc[4]);  acc[5] = fmaf(xv, wb.y, acc[5]);
                acc[6] = fmaf(xv, wb.z, acc[6]);  acc[7] = fmaf(xv, wb.w, acc[7]);
                acc[8] = fmaf(xv, wc.x, acc[8]);  acc[9] = fmaf(xv, wc.y, acc[9]);
                acc[10] = fmaf(xv, wc.z, acc[10]); acc[11] = fmaf(xv, wc.w, acc[11]);
                acc[12] = fmaf(xv, wd.x, acc[12]); acc[13] = fmaf(xv, wd.y, acc[13]);
                acc[14] = fmaf(xv, wd.z, acc[14]); acc[15] = fmaf(xv, wd.w, acc[15]);
            }
        }
        __syncthreads();               // w1s dead; reuse as reduction sp
        float* sp = (float*)w1s;       // [8 subs][16 j][32 c] = 4096 floats
#pragma unroll
        for (int j = 0; j < NHID_; ++j) sp[sub * 512 + j * 32 + c32] = acc[j];
        __syncthreads();
        for (int i = t; i < 512; i += 256) {
            int j = i >> 5, cc = i & 31;
            float v = 0.f;
#pragma unroll
            for (int s = 0; s < 8; ++s) v += sp[s * 512 + j * 32 + cc];
            atomicAdd(&hT[j * C_ + cg * 64 + half * 32 + cc], v);
        }
    } else {
        // ---- per-bucket frag counts -> u8 ----
        int bk = bid - 512, cg = bk >> 4, gc = bk & 15;
        for (int i = t; i < 2048; i += 256) h[i] = 0;
        __syncthreads();
        unsigned int count = gcnt_f[bk];
        if (count > RCAP_FRAG) count = RCAP_FRAG;
        const unsigned short* e = entf + (size_t)bk * RCAP_FRAG;
#pragma unroll 4
        for (unsigned int p = t; p < count; p += 256) {
            unsigned int v = e[p];
            unsigned int g_lo = v & 63u;
            unsigned int c_lo = (v >> 6) & 63u;
            atomicAdd(&h[g_lo * 32 + (c_lo >> 1)], 1u << ((c_lo & 1) * 16));
        }
        __syncthreads();
        for (int i = t; i < 1024; i += 256) {
            int g_lo = i >> 4, wb = i & 15;
            unsigned int lo = h[g_lo * 32 + wb * 2];
            unsigned int hi = h[g_lo * 32 + wb * 2 + 1];
            unsigned int outv = (lo & 0xffu) | (((lo >> 16) & 0xffu) << 8)
                              | ((hi & 0xffu) << 16) | (((hi >> 16) & 0xffu) << 24);
            int g = gc * 64 + g_lo;
            if (g < G_)
                fragw[(unsigned)g * 256u + (unsigned)cg * 16u + wb] = outv;
        }
    }
}

// --- 3. latent: BN stats from hT (f64, per block) + sample + KL ------------
__global__ __launch_bounds__(256)
void latent_kernel(const float* __restrict__ hT,     // [16][1024]
                   const float* __restrict__ gamma,
                   const float* __restrict__ beta,
                   const float* __restrict__ W_loc,   // [16][50]
                   const float* __restrict__ b_loc,
                   const float* __restrict__ W_scale, // [16][50]
                   const float* __restrict__ b_scale,
                   const float* __restrict__ eps,     // [1024][50]
                   float* __restrict__ latT,          // [50][1024]
                   __hip_bfloat16* __restrict__ latbf,// [1024][64]
                   double* __restrict__ dacc) {       // [64]
    __shared__ float scs[NHID_], shs[NHID_];
    int t = threadIdx.x;
    {   // phase 1: per-block redundant BN stats (hT is 64 KB, L2-hot)
        int j = t >> 4, cl = t & 15;
        double s1 = 0.0, s2 = 0.0;
#pragma unroll 8
        for (int k = 0; k < 64; ++k) {
            float v = hT[j * C_ + cl + k * 16];
            s1 += (double)v; s2 += (double)v * (double)v;
        }
#pragma unroll
        for (int m = 1; m < 16; m <<= 1) {   // reduce 16-lane groups (same j)
            s1 += __shfl_xor(s1, m);
            s2 += __shfl_xor(s2, m);
        }
        if (cl == 0) {
            double mean = s1 * (1.0 / C_);
            double var = s2 * (1.0 / C_) - mean * mean;
            float rstd = rsqrtf((float)var + 1e-5f);
            float sc = gamma[j] * rstd;
            scs[j] = sc;
            shs[j] = beta[j] - (float)mean * sc;
        }
    }
    __syncthreads();
    int idx = blockIdx.x * 256 + t;
    float kl = 0.f;
    {
        int c = idx / L_;
        int l = idx - c * L_;
        float hb[NHID_];
#pragma unroll
        for (int j = 0; j < NHID_; ++j) {
            float v = fmaf(hT[j * C_ + c], scs[j], shs[j]);
            hb[j] = v > 0.f ? v : 0.f;
        }
        float loc = b_loc[l], ls = b_scale[l];
#pragma unroll
        for (int j = 0; j < NHID_; ++j) {
            loc = fmaf(hb[j], W_loc[j * L_ + l], loc);
            ls  = fmaf(hb[j], W_scale[j * L_ + l], ls);
        }
        float qs = 0.1f * __expf(ls);
        float e = eps[idx];
        float lat = fmaf(qs, e, loc);
        latT[(size_t)l * C_ + c] = lat;
        latbf[c * 64 + l] = __float2bfloat16(lat);
        if (l < 14) latbf[c * 64 + 50 + l] = __float2bfloat16(0.f);  // k-pad
        float z = (lat - loc) / qs;
        kl = fmaf(-0.5f * lat, lat, fmaf(0.5f * z, z, __logf(qs)));
    }
    float s = block_sum_256(kl);
    if (threadIdx.x == 0)
        atomAddF64(&dacc[blockIdx.x & 63], (double)(-CELL_SCALE * s));
}

// --- 4. mixture (swapped-operand MFMA, lane-local softmax) + Poisson -------
// grid (1000, 2), 512 cells/block; merged layout [cg*2+half][bin][4w].
// r24: all 32 merged words prefetched before the MFMA loop (addresses are
// MFMA-independent) — hides ~200cy L2 latency under the MFMA/softmax chain.
__global__ __launch_bounds__(256)
void mixpois_kernel(const __hip_bfloat16* __restrict__ latbf, // [1024][64]
                    const __hip_bfloat16* __restrict__ lwT,   // [1000][16][64]
                    const unsigned int* __restrict__ merged,  // [32][16000][4]
                    const float* __restrict__ baseline,       // [1000][16]
                    const float* __restrict__ latT,           // [50][1024]
                    const float* __restrict__ rw,             // [1000][50]
                    const float* __restrict__ rho_bias,
                    const int* __restrict__ libsize,
                    const unsigned char* __restrict__ fragb,  // [1000][1024]
                    double* __restrict__ dacc,                // [64]
                    unsigned int* __restrict__ done,          // zeroed
                    float* __restrict__ out) {
    int g = blockIdx.x;
    int y = blockIdx.y;
    int t = threadIdx.x;
    int lane = t & 63;
    int wv = t >> 6;
    int s16 = lane & 15;           // A row sel (comp) AND B col sel (cell)
    int quad = lane >> 4;
    const __hip_bfloat16* bb = lwT + (size_t)g * 1024 + s16 * 64 + quad * 8;
    short8 lw1 = *(const short8*)bb;
    short8 lw2 = *(const short8*)(bb + 32);
    const float4 bl4 = *(const float4*)(baseline + g * K_ + quad * 4);
    const unsigned int gb = ((unsigned)(g * K_ + quad * 4)) * 4u;  // bin base
    int cwave = y * 512 + wv * 128;
    // r24: prefetch all 32 merged words up-front (independent of MFMA)
    unsigned int mw[8][4];
#pragma unroll
    for (int mt = 0; mt < 8; ++mt) {
        int cp = cwave + mt * 16 + s16;
        unsigned int base2 = ((unsigned)cp >> 5) * 64000u
                           + (((unsigned)cp & 31u) >> 3);
#pragma unroll
        for (int r = 0; r < 4; ++r)
            mw[mt][r] = merged[base2 + gb + r * 4u];
    }
    float partial = 0.f;
#pragma unroll
    for (int mt = 0; mt < 8; ++mt) {
        int c0 = cwave + mt * 16;
        const __hip_bfloat16* aa = latbf + (size_t)(c0 + s16) * 64 + quad * 8;
        short8 la1 = *(const short8*)aa;
        short8 la2 = *(const short8*)(aa + 32);
        f32x4 d = {bl4.x, bl4.y, bl4.z, bl4.w};
        d = __builtin_amdgcn_mfma_f32_16x16x32_bf16(lw1, la1, d, 0, 0, 0);
        d = __builtin_amdgcn_mfma_f32_16x16x32_bf16(lw2, la2, d, 0, 0, 0);
        float m = fmaxf(fmaxf(d[0], d[1]), fmaxf(d[2], d[3]));
        m = fmaxf(m, __shfl_xor(m, 16));
        m = fmaxf(m, __shfl_xor(m, 32));
        float e0 = __expf(d[0] - m), e1 = __expf(d[1] - m);
        float e2 = __expf(d[2] - m), e3 = __expf(d[3] - m);
        float S = (e0 + e1) + (e2 + e3);
        S += __shfl_xor(S, 16);
        S += __shfl_xor(S, 32);
        float lse = m + __logf(S);
        int cp = c0 + s16;
        int sb = (cp & 7) * 4;
#pragma unroll
        for (int r = 0; r < 4; ++r) {
            float cnt = (float)((mw[mt][r] >> sb) & 0xfu);
            partial = fmaf(cnt, d[r] - lse, partial);
        }
    }
    // ---- Poisson for the same 512-cell tile (2 cells/thread) ----
    float v;
    {
        const float* rwg = rw + (size_t)g * L_;   // hoists to SGPRs
        int cA = y * 512 + t, cB = cA + 256;
        float rhoA = 0.f, rhoB = 0.f;
#pragma unroll 10
        for (int l = 0; l < L_; ++l) {
            float wl = rwg[l];
            rhoA = fmaf(latT[l * C_ + cA], wl, rhoA);
            rhoB = fmaf(latT[l * C_ + cB], wl, rhoB);
        }
        unsigned int fcA = fragb[(size_t)g * C_ + cA];
        unsigned int fcB = fragb[(size_t)g * C_ + cB];
        float rb = rho_bias[g];
        float feA = rb * __expf(rhoA) * (float)libsize[cA];
        float feB = rb * __expf(rhoB) * (float)libsize[cB];
        float lfA = fmaf((float)fcA, __logf(feA), -feA) - LGT[fcA > 31u ? 31u : fcA];
        float lfB = fmaf((float)fcB, __logf(feB), -feB) - LGT[fcB > 31u ? 31u : fcB];
        v = fmaf(-CUT_SCALE, partial, -CELL_SCALE * (lfA + lfB));
    }
    float contrib = block_sum_256(v);
    // ---- fence-free fused final: atomic f64 accumulate + 2-level counter --
    __shared__ int lastflag;
    if (threadIdx.x == 0) {
        lastflag = 0;
        int slot = blockIdx.x & 63;
        double oldv = atomAddF64(&dacc[slot], (double)contrib);
        unsigned inc = 1u;
        float dep = (float)oldv;
        asm volatile("" : "+v"(inc) : "v"(dep));
        unsigned quota = ((slot < 40) ? 16u : 15u) * 2u;   // 1000 = 15*64+40
        if (atomicAdd(&done[slot * 16], inc) == quota - 1u) {
            if (atomicAdd(&done[1024], 1u) == 63u) lastflag = 1;
        }
    }
    __syncthreads();
    if (lastflag) {
        if (t < 64) {
            double dv = atomAddF64(&dacc[t], 0.0);
#pragma unroll
            for (int m = 1; m < 64; m <<= 1) dv += __shfl_xor(dv, m);
            if (t == 0)
                out[0] = (float)(dv - 138629436.11198905); // -12.5*4e6*log16
        }
    }
}

extern "C" void kernel_launch(void* const* d_in, const int* in_sizes, int n_in,
                              void* d_out, int out_size, void* d_ws, size_t ws_size,
                              hipStream_t stream) {
    const float* cut_coord = (const float*)d_in[0];
    const float* eps       = (const float*)d_in[1];
    const float* enc_W1    = (const float*)d_in[2];
    // d_in[3] = enc_b1 : cancels through BatchNorm, unused
    const float* bn_gamma  = (const float*)d_in[4];
    const float* bn_beta   = (const float*)d_in[5];
    const float* W_loc     = (const float*)d_in[6];
    const float* b_loc     = (const float*)d_in[7];
    const float* W_scale   = (const float*)d_in[8];
    const float* b_scale   = (const float*)d_in[9];
    const float* logit_w   = (const float*)d_in[10];
    const float* rho_w     = (const float*)d_in[11];
    const float* baseline  = (const float*)d_in[12];
    const float* rho_bias  = (const float*)d_in[13];
    const int* cut_cxg     = (const int*)d_in[14];
    const int* frag_ix     = (const int*)d_in[16];
    const int* libsize     = (const int*)d_in[19];

    int n_cuts  = in_sizes[0];
    int n_frags = in_sizes[16];

    char* ws = (char*)d_ws;
    unsigned int*   gcnt_c = (unsigned int*)(ws + GCNTC_OFF);
    unsigned int*   gcnt_f = (unsigned int*)(ws + GCNTF_OFF);
    unsigned int*   done   = (unsigned int*)(ws + DONE_OFF);
    double*         dacc   = (double*)(ws + DACC_OFF);
    float*          hT     = (float*)(ws + HT_OFF);
    __hip_bfloat16* latbf  = (__hip_bfloat16*)(ws + LATBF_OFF);
    __hip_bfloat16* lwT    = (__hip_bfloat16*)(ws + LWT_OFF);
    unsigned short* entc   = (unsigned short*)(ws + ENTC_OFF);
    unsigned short* entf   = (unsigned short*)(ws + ENTF_OFF);
    unsigned int*   merged = (unsigned int*)(ws + MERGED_OFF);
    unsigned int*   fragw  = (unsigned int*)(ws + FRAGU8_OFF);
    float*          latT   = (float*)(ws + LATT_OFF);
    float*          out    = (float*)d_out;

    int ncc = (n_cuts + CHUNK_ - 1) / CHUNK_;
    int ncf = (n_frags + CHUNK_ - 1) / CHUNK_;
    int nblk_part = ncc + ncf;

    hipMemsetAsync(ws, 0, ZERO_BYTES, stream);   // gcnt + done + dacc + hT

    part_kernel<<<nblk_part + 512, 256, 0, stream>>>(
        cut_cxg, cut_coord, frag_ix, gcnt_c, gcnt_f, entc, entf,
        logit_w, rho_w, lwT, dacc,
        n_cuts, n_frags, ncc, nblk_part);
    mid_kernel<<<768, 256, 0, stream>>>(
        gcnt_c, entc, gcnt_f, entf, enc_W1, merged, fragw, hT);
    latent_kernel<<<(C_ * L_) / 256, 256, 0, stream>>>(
        hT, bn_gamma, bn_beta, W_loc, b_loc, W_scale, b_scale,
        eps, latT, latbf, dacc);
    mixpois_kernel<<<dim3(G_, 2), 256, 0, stream>>>(
        latbf, lwT, merged, baseline, latT, rho_w, rho_bias, libsize,
        (const unsigned char*)fragw, dacc, done, out);
}